// Round 6
// baseline (337.696 us; speedup 1.0000x reference)
//
#include <hip/hip_runtime.h>
#include <math.h>

#define Bn 16
#define Hh 512
#define Ww 512
#define HW_ (Hh * Ww)
#define TW 32                // tile width
#define TH 16                // tile height
#define NTHREADS 512
#define TPB 8                // tiles walked per block (vertical)
#define S 37                 // unified grid stride (input halo & feat grids)
#define NROWS 20             // input halo rows (TH+4)
#define NVALID (NROWS * S)   // 740 staged halo positions
#define SIN_N 912            // s_in entries allocated (max read idx 880)
#define NFP 800              // feat positions per 8-ch half (48 tiles * 16 = 768, pad)
#define SMEM_BYTES (SIN_N * 16 + 2 * NFP * 16)   // 14592 + 25600 = 40192 -> 4 blocks/CU

typedef __bf16 bfrag __attribute__((ext_vector_type(8)));
typedef __bf16 bf4   __attribute__((ext_vector_type(4)));
typedef float  ffrag __attribute__((ext_vector_type(16)));
typedef float  f32x4 __attribute__((ext_vector_type(4)));
typedef float  f32x2 __attribute__((ext_vector_type(2)));

__device__ __forceinline__ short f2bf(float f) {           // RNE fp32 -> bf16 bits
    unsigned u = __float_as_uint(f);
    unsigned r = u + 0x7FFFu + ((u >> 16) & 1u);
    return (short)(r >> 16);
}

__device__ __forceinline__ f32x2 mk2(float a, float b) { f32x2 t; t.x = a; t.y = b; return t; }

// gelu exact-form via trans-free erf polynomial (same numerics as R3/R4)
__device__ __forceinline__ f32x2 gelu_fast2(f32x2 x) {
    const float C0 = 1.1259890f, C1 = -0.3565430f, C2 = 0.0848830f,
                C3 = -0.0110610f, C4 = 0.0005820f;
    f32x2 y = x * 0.70710678f;
    f32x2 t;
    t.x = fminf(fmaxf(y.x, -2.5f), 2.5f);
    t.y = fminf(fmaxf(y.y, -2.5f), 2.5f);
    f32x2 u = t * t;
    f32x2 p = u * C4 + C3;
    p = p * u + C2;
    p = p * u + C1;
    p = p * u + C0;
    f32x2 e = t * p;                 // ~erf(y)
    f32x2 h = x * 0.5f;
    return h * e + h;                // 0.5x(1+erf)
}

__device__ __forceinline__ float bilin(const float* __restrict__ img, float py, float px) {
    float y0f = floorf(py), x0f = floorf(px);
    float wy = py - y0f, wx = px - x0f;
    int y0 = (int)y0f, x0 = (int)x0f;
    int yc0 = min(max(y0, 0), Hh - 1), yc1 = min(max(y0 + 1, 0), Hh - 1);
    int xc0 = min(max(x0, 0), Ww - 1), xc1 = min(max(x0 + 1, 0), Ww - 1);
    bool vy0 = (unsigned)y0 < (unsigned)Hh, vy1 = (unsigned)(y0 + 1) < (unsigned)Hh;
    bool vx0 = (unsigned)x0 < (unsigned)Ww, vx1 = (unsigned)(x0 + 1) < (unsigned)Ww;
    const float* r0 = img + yc0 * Ww;
    const float* r1 = img + yc1 * Ww;
    float v00 = (vy0 && vx0) ? r0[xc0] : 0.0f;
    float v01 = (vy0 && vx1) ? r0[xc1] : 0.0f;
    float v10 = (vy1 && vx0) ? r1[xc0] : 0.0f;
    float v11 = (vy1 && vx1) ? r1[xc1] : 0.0f;
    return (1.0f - wy) * ((1.0f - wx) * v00 + wx * v01) +
           wy          * ((1.0f - wx) * v10 + wx * v11);
}

// ---- pre-pass: pack w2 A-frags (9 taps, 32x32x16) + w1 A-frags (2, 16x16x32) ----
__global__ void pack_w(const float* __restrict__ w2, const float* __restrict__ w1,
                       const float* __restrict__ b1, int* __restrict__ ws) {
    const int lane = threadIdx.x;            // 64 threads
    const int l31  = lane & 31;
    const int lh   = lane >> 5;
    for (int tap = 0; tap < 9; ++tap) {
        int pk[4];
        #pragma unroll
        for (int jj = 0; jj < 4; ++jj) {
            float v0 = (l31 < 18) ? w2[(l31 * 16 + lh * 8 + 2 * jj    ) * 9 + tap] : 0.0f;
            float v1 = (l31 < 18) ? w2[(l31 * 16 + lh * 8 + 2 * jj + 1) * 9 + tap] : 0.0f;
            pk[jj] = ((int)(unsigned short)f2bf(v0)) | ((int)f2bf(v1) << 16);
        }
        ((int4*)ws)[tap * 64 + lane] = make_int4(pk[0], pk[1], pk[2], pk[3]);
    }
    const int m  = lane & 15;
    const int kq = lane >> 4;
    for (int t = 0; t < 2; ++t) {
        int pk[4];
        #pragma unroll
        for (int jj = 0; jj < 4; ++jj) {
            float vv[2];
            #pragma unroll
            for (int h = 0; h < 2; ++h) {
                int k   = kq * 8 + 2 * jj + h;
                int kyl = k >> 4, kx = (k >> 2) & 3, c = k & 3;
                int ky  = 2 * t + kyl;
                float x = 0.0f;
                if (kx < 3 && c < 3 && ky < 3) x = w1[m * 27 + c * 9 + ky * 3 + kx];
                if (t == 0 && k == 3) x = b1[m];     // bias slot (reads const-1.0 channel)
                vv[h] = x;
            }
            pk[jj] = ((int)(unsigned short)f2bf(vv[0])) | ((int)f2bf(vv[1]) << 16);
        }
        ((int4*)ws)[576 + t * 64 + lane] = make_int4(pk[0], pk[1], pk[2], pk[3]);
    }
}

__global__ __launch_bounds__(NTHREADS, 8) void residual_advection_fused(
    const float* __restrict__ pm25,   // (16,1,512,512)
    const float* __restrict__ wind,   // (16,2,512,512)
    const float* __restrict__ topo,   // (16,1,512,512)
    const float* __restrict__ b2,     // (18)
    const float* __restrict__ wt,     // (9)
    const int*   __restrict__ wsB,    // packed w2 + w1 A-fragments
    float* __restrict__ out)          // (16,1,512,512)
{
    __shared__ __align__(16) char smem[SMEM_BYTES];
    __bf16* s_in   = (__bf16*)smem;                  // dup entries, 16B each
    __bf16* s_feat = (__bf16*)(smem + SIN_N * 16);   // [2][NFP][8]

    const int tid = threadIdx.x;
    const int bb  = blockIdx.z;
    const int tx0 = blockIdx.x * TW;
    int ty0 = blockIdx.y * (TPB * TH);

    const int lane = tid & 63;
    const int wv   = tid >> 6;       // 0..7
    const int l31  = lane & 31;
    const int lh   = lane >> 5;

    const bfrag* WF = (const bfrag*)wsB;
    bfrag w1f0 = WF[576 + lane];
    bfrag w1f1 = WF[640 + lane];

    // ---- one-time zero-fill of dup-layout bytes the per-iteration commit never
    // writes: positions NVALID..SIN_N-1 -> entry 739 high-8B .. entry 911 low-8B.
    // (P2 over-reach tiles + the ky=3 zero-weight row read these; MFMA 0*NaN=NaN,
    // so they must be real zeros. Ordered before first use by barrier B1.)
    {
        bf4 z;
        z[0] = (__bf16)0.0f; z[1] = (__bf16)0.0f; z[2] = (__bf16)0.0f; z[3] = (__bf16)0.0f;
        for (int pos = NVALID + tid; pos < SIN_N; pos += NTHREADS) {
            *(bf4*)&s_in[pos * 8] = z;         // entry pos, low 8B
            *(bf4*)&s_in[pos * 8 - 4] = z;     // entry pos-1, high 8B
        }
    }

    // loop-invariant staging coordinates (2 halo entries per thread)
    const int rA = tid / S, cA = tid - rA * S;
    const int tidB = tid + NTHREADS;
    const int rB = tidB / S, cB = tidB - rB * S;
    const bool haveB = tidB < NVALID;
    const int gxA = tx0 - 2 + cA;  const bool vxA = (unsigned)gxA < (unsigned)Ww;
    const int gxB = tx0 - 2 + cB;  const bool vxB = (unsigned)gxB < (unsigned)Ww;
    const float* wp0 = wind + (bb * 2 + 0) * HW_;
    const float* wp1 = wind + (bb * 2 + 1) * HW_;
    const float* tp  = topo + bb * HW_;
    const float* img = pm25 + bb * HW_;

    float sa0, sa1, sa2, sb0, sb1, sb2;
    auto stage = [&](int ty) {
        int gyA = ty - 2 + rA;
        bool vA = vxA && (unsigned)gyA < (unsigned)Hh;
        sa0 = 0.0f; sa1 = 0.0f; sa2 = 0.0f;
        if (vA) { int g = gyA * Ww + gxA; sa0 = wp0[g]; sa1 = wp1[g]; sa2 = tp[g]; }
        sb0 = 0.0f; sb1 = 0.0f; sb2 = 0.0f;
        if (haveB) {
            int gyB = ty - 2 + rB;
            bool vB = vxB && (unsigned)gyB < (unsigned)Hh;
            if (vB) { int g = gyB * Ww + gxB; sb0 = wp0[g]; sb1 = wp1[g]; sb2 = tp[g]; }
        }
    };

    stage(ty0);                        // prologue prefetch

    for (int it = 0; it < TPB; ++it) {
        // ---- A: commit staged halo regs to LDS (dup-entry layout) ----
        {
            bf4 v;
            v[0] = (__bf16)sa0; v[1] = (__bf16)sa1; v[2] = (__bf16)sa2; v[3] = (__bf16)1.0f;
            *(bf4*)&s_in[tid * 8] = v;
            if (tid > 0) *(bf4*)&s_in[tid * 8 - 4] = v;
            if (haveB) {
                bf4 w;
                w[0] = (__bf16)sb0; w[1] = (__bf16)sb1; w[2] = (__bf16)sb2; w[3] = (__bf16)1.0f;
                *(bf4*)&s_in[tidB * 8] = w;
                *(bf4*)&s_in[tidB * 8 - 4] = w;
            }
        }
        __syncthreads();               // B1: s_in ready; fences prev P3 feat reads too

        // ---- prefetch next tile's halo (covered by P2+P3+P4; drained by P4's vmcnt) ----
        if (it + 1 < TPB) stage(ty0 + TH);

        const bool edge = (ty0 == 0) || (ty0 == Hh - TH) || (tx0 == 0) || (tx0 == Ww - TW);

        // ---- P2: conv1 via MFMA 16x16x32, fully unrolled 6 tiles/wave ----
        {
            const int n    = lane & 15;
            const int kq   = lane >> 4;
            const int qoff = (kq >> 1) * S + (kq & 1) * 2;
            #pragma unroll
            for (int ii = 0; ii < 6; ++ii) {
                const int p = (wv + 8 * ii) * 16 + n;       // p <= 767 (tiles >= 42 unused)
                f32x4 acc;
                acc[0] = 0.0f; acc[1] = 0.0f; acc[2] = 0.0f; acc[3] = 0.0f;
                bfrag bx0 = *(const bfrag*)&s_in[(p + qoff) * 8];
                bfrag bx1 = *(const bfrag*)&s_in[(p + qoff + 2 * S) * 8];
                acc = __builtin_amdgcn_mfma_f32_16x16x32_bf16(w1f0, bx0, acc, 0, 0, 0);
                acc = __builtin_amdgcn_mfma_f32_16x16x32_bf16(w1f1, bx1, acc, 0, 0, 0);
                f32x2 g0 = gelu_fast2(mk2(acc[0], acc[1]));
                f32x2 g1 = gelu_fast2(mk2(acc[2], acc[3]));
                if (edge) {
                    int fy = p / S;
                    int fx = p - fy * S;
                    int gy = ty0 + fy - 1, gx = tx0 + fx - 1;
                    float msk = ((unsigned)gy < (unsigned)Hh && (unsigned)gx < (unsigned)Ww)
                                ? 1.0f : 0.0f;
                    g0 *= msk; g1 *= msk;
                }
                bf4 w4;
                w4[0] = (__bf16)g0.x; w4[1] = (__bf16)g0.y;
                w4[2] = (__bf16)g1.x; w4[3] = (__bf16)g1.y;
                *(bf4*)&s_feat[((kq >> 1) * NFP + p) * 8 + (kq & 1) * 4] = w4;
            }
        }
        __syncthreads();               // B2: s_feat ready; fences s_in reads for next A

        // ---- P3: conv2 via MFMA 32x32x16, 12 shared fragments ----
        ffrag a0, a1;
        #pragma unroll
        for (int r = 0; r < 16; ++r) { a0[r] = 0.0f; a1[r] = 0.0f; }
        {
            const int vb = (lh * NFP + (2 * wv) * S + l31) * 8;
            #pragma unroll
            for (int kx = 0; kx < 3; ++kx) {
                bfrag f0 = *(const bfrag*)&s_feat[vb + (0 * S + kx) * 8];
                bfrag f1 = *(const bfrag*)&s_feat[vb + (1 * S + kx) * 8];
                bfrag f2 = *(const bfrag*)&s_feat[vb + (2 * S + kx) * 8];
                bfrag f3 = *(const bfrag*)&s_feat[vb + (3 * S + kx) * 8];
                bfrag w0  = WF[(0 * 3 + kx) * 64 + lane];
                bfrag w1_ = WF[(1 * 3 + kx) * 64 + lane];
                bfrag w2_ = WF[(2 * 3 + kx) * 64 + lane];
                a0 = __builtin_amdgcn_mfma_f32_32x32x16_bf16(w0,  f0, a0, 0, 0, 0);
                a1 = __builtin_amdgcn_mfma_f32_32x32x16_bf16(w0,  f1, a1, 0, 0, 0);
                a0 = __builtin_amdgcn_mfma_f32_32x32x16_bf16(w1_, f1, a0, 0, 0, 0);
                a1 = __builtin_amdgcn_mfma_f32_32x32x16_bf16(w1_, f2, a1, 0, 0, 0);
                a0 = __builtin_amdgcn_mfma_f32_32x32x16_bf16(w2_, f2, a0, 0, 0, 0);
                a1 = __builtin_amdgcn_mfma_f32_32x32x16_bf16(w2_, f3, a1, 0, 0, 0);
            }
        }

        // ---- P4: lazy per-active-tap exchange, one bilinear sample per lane ----
        {
            const int py_i = ty0 + 2 * wv + lh;
            const int px_i = tx0 + l31;
            const float fy = (float)py_i, fx = (float)px_i;
            float o = 0.0f;
            #pragma unroll
            for (int t = 0; t < 9; ++t) {
                float wk = wt[t];                        // uniform -> scalar branch
                if (wk != 0.0f) {
                    const int o_h = (t >> 1) & 1;                  // owner lane-half
                    const int rg  = ((2 * t) & 3) + 4 * (t >> 2);  // dy reg; dx = rg+1
                    float dy, dx;
                    if (o_h == 0) {
                        float sy = __shfl_xor(a1[rg], 32);
                        float sx = __shfl_xor(a1[rg + 1], 32);
                        dy = lh ? sy : a0[rg];
                        dx = lh ? sx : a0[rg + 1];
                    } else {
                        float sy = __shfl_xor(a0[rg], 32);
                        float sx = __shfl_xor(a0[rg + 1], 32);
                        dy = lh ? a1[rg] : sy;
                        dx = lh ? a1[rg + 1] : sx;
                    }
                    dy += b2[2 * t];
                    dx += b2[2 * t + 1];
                    float py = fy + (float)(t / 3 - 1) + dy;
                    float px = fx + (float)(t % 3 - 1) + dx;
                    o += wk * bilin(img, py, px);
                }
            }
            out[bb * HW_ + py_i * Ww + px_i] = o;
        }

        ty0 += TH;
    }
}

extern "C" void kernel_launch(void* const* d_in, const int* in_sizes, int n_in,
                              void* d_out, int out_size, void* d_ws, size_t ws_size,
                              hipStream_t stream) {
    const float* pm25 = (const float*)d_in[0];
    const float* wind = (const float*)d_in[1];
    const float* topo = (const float*)d_in[2];
    const float* w1   = (const float*)d_in[3];
    const float* b1   = (const float*)d_in[4];
    const float* w2   = (const float*)d_in[5];
    const float* b2   = (const float*)d_in[6];
    const float* wt   = (const float*)d_in[7];
    float* o          = (float*)d_out;
    int*   wsB        = (int*)d_ws;   // 576+128 int4 = 11264 B

    pack_w<<<dim3(1), dim3(64), 0, stream>>>(w2, w1, b1, wsB);

    dim3 grid(Ww / TW, Hh / (TH * TPB), Bn);   // 16 x 4 x 16 = 1024 blocks = 4/CU
    residual_advection_fused<<<grid, dim3(NTHREADS), 0, stream>>>(
        pm25, wind, topo, b2, wt, wsB, o);
}

// Round 7
// 302.717 us; speedup vs baseline: 1.1155x; 1.1155x over previous
//
#include <hip/hip_runtime.h>
#include <math.h>

#define Bn 16
#define Hh 512
#define Ww 512
#define HW_ (Hh * Ww)
#define TW 32                // tile width
#define TH 16                // tile height
#define NTHREADS 512
#define TPB 8                // tiles walked per block (vertical)
#define S 37                 // unified grid stride (input halo & feat grids)
#define NROWS 20             // input halo rows (TH+4)
#define NVALID (NROWS * S)   // 740 staged halo positions
#define SIN_N 912            // s_in entries allocated (max read idx 880)
#define NFP 800              // feat positions per 8-ch half (48 tiles * 16 = 768, pad)
#define SMEM_BYTES (SIN_N * 16 + 2 * NFP * 16)   // 14592 + 25600 = 40192 -> 3 blocks/CU

typedef __bf16 bfrag __attribute__((ext_vector_type(8)));
typedef __bf16 bf4   __attribute__((ext_vector_type(4)));
typedef float  ffrag __attribute__((ext_vector_type(16)));
typedef float  f32x4 __attribute__((ext_vector_type(4)));
typedef float  f32x2 __attribute__((ext_vector_type(2)));

__device__ __forceinline__ short f2bf(float f) {           // RNE fp32 -> bf16 bits
    unsigned u = __float_as_uint(f);
    unsigned r = u + 0x7FFFu + ((u >> 16) & 1u);
    return (short)(r >> 16);
}

__device__ __forceinline__ f32x2 mk2(float a, float b) { f32x2 t; t.x = a; t.y = b; return t; }

// gelu exact-form via trans-free erf polynomial (same numerics as R3/R4)
__device__ __forceinline__ f32x2 gelu_fast2(f32x2 x) {
    const float C0 = 1.1259890f, C1 = -0.3565430f, C2 = 0.0848830f,
                C3 = -0.0110610f, C4 = 0.0005820f;
    f32x2 y = x * 0.70710678f;
    f32x2 t;
    t.x = fminf(fmaxf(y.x, -2.5f), 2.5f);
    t.y = fminf(fmaxf(y.y, -2.5f), 2.5f);
    f32x2 u = t * t;
    f32x2 p = u * C4 + C3;
    p = p * u + C2;
    p = p * u + C1;
    p = p * u + C0;
    f32x2 e = t * p;                 // ~erf(y)
    f32x2 h = x * 0.5f;
    return h * e + h;                // 0.5x(1+erf)
}

__device__ __forceinline__ float bilin(const float* __restrict__ img, float py, float px) {
    float y0f = floorf(py), x0f = floorf(px);
    float wy = py - y0f, wx = px - x0f;
    int y0 = (int)y0f, x0 = (int)x0f;
    int yc0 = min(max(y0, 0), Hh - 1), yc1 = min(max(y0 + 1, 0), Hh - 1);
    int xc0 = min(max(x0, 0), Ww - 1), xc1 = min(max(x0 + 1, 0), Ww - 1);
    bool vy0 = (unsigned)y0 < (unsigned)Hh, vy1 = (unsigned)(y0 + 1) < (unsigned)Hh;
    bool vx0 = (unsigned)x0 < (unsigned)Ww, vx1 = (unsigned)(x0 + 1) < (unsigned)Ww;
    const float* r0 = img + yc0 * Ww;
    const float* r1 = img + yc1 * Ww;
    float v00 = (vy0 && vx0) ? r0[xc0] : 0.0f;
    float v01 = (vy0 && vx1) ? r0[xc1] : 0.0f;
    float v10 = (vy1 && vx0) ? r1[xc0] : 0.0f;
    float v11 = (vy1 && vx1) ? r1[xc1] : 0.0f;
    return (1.0f - wy) * ((1.0f - wx) * v00 + wx * v01) +
           wy          * ((1.0f - wx) * v10 + wx * v11);
}

// ---- pre-pass: pack w2 A-frags (9 taps, 32x32x16) + w1 A-frags (2, 16x16x32) ----
__global__ void pack_w(const float* __restrict__ w2, const float* __restrict__ w1,
                       const float* __restrict__ b1, int* __restrict__ ws) {
    const int lane = threadIdx.x;            // 64 threads
    const int l31  = lane & 31;
    const int lh   = lane >> 5;
    for (int tap = 0; tap < 9; ++tap) {
        int pk[4];
        #pragma unroll
        for (int jj = 0; jj < 4; ++jj) {
            float v0 = (l31 < 18) ? w2[(l31 * 16 + lh * 8 + 2 * jj    ) * 9 + tap] : 0.0f;
            float v1 = (l31 < 18) ? w2[(l31 * 16 + lh * 8 + 2 * jj + 1) * 9 + tap] : 0.0f;
            pk[jj] = ((int)(unsigned short)f2bf(v0)) | ((int)f2bf(v1) << 16);
        }
        ((int4*)ws)[tap * 64 + lane] = make_int4(pk[0], pk[1], pk[2], pk[3]);
    }
    const int m  = lane & 15;
    const int kq = lane >> 4;
    for (int t = 0; t < 2; ++t) {
        int pk[4];
        #pragma unroll
        for (int jj = 0; jj < 4; ++jj) {
            float vv[2];
            #pragma unroll
            for (int h = 0; h < 2; ++h) {
                int k   = kq * 8 + 2 * jj + h;
                int kyl = k >> 4, kx = (k >> 2) & 3, c = k & 3;
                int ky  = 2 * t + kyl;
                float x = 0.0f;
                if (kx < 3 && c < 3 && ky < 3) x = w1[m * 27 + c * 9 + ky * 3 + kx];
                if (t == 0 && k == 3) x = b1[m];     // bias slot (reads const-1.0 channel)
                vv[h] = x;
            }
            pk[jj] = ((int)(unsigned short)f2bf(vv[0])) | ((int)f2bf(vv[1]) << 16);
        }
        ((int4*)ws)[576 + t * 64 + lane] = make_int4(pk[0], pk[1], pk[2], pk[3]);
    }
}

__global__ __launch_bounds__(NTHREADS, 6) void residual_advection_fused(
    const float* __restrict__ pm25,   // (16,1,512,512)
    const float* __restrict__ wind,   // (16,2,512,512)
    const float* __restrict__ topo,   // (16,1,512,512)
    const float* __restrict__ b2,     // (18)
    const float* __restrict__ wt,     // (9)
    const int*   __restrict__ wsB,    // packed w2 + w1 A-fragments
    float* __restrict__ out)          // (16,1,512,512)
{
    __shared__ __align__(16) char smem[SMEM_BYTES];
    __bf16* s_in   = (__bf16*)smem;                  // dup entries, 16B each
    __bf16* s_feat = (__bf16*)(smem + SIN_N * 16);   // [2][NFP][8]

    const int tid = threadIdx.x;
    const int bb  = blockIdx.z;
    const int tx0 = blockIdx.x * TW;
    int ty0 = blockIdx.y * (TPB * TH);

    const int lane = tid & 63;
    const int wv   = tid >> 6;       // 0..7
    const int l31  = lane & 31;
    const int lh   = lane >> 5;

    const bfrag* WF = (const bfrag*)wsB;
    bfrag w1f0 = WF[576 + lane];
    bfrag w1f1 = WF[640 + lane];

    // ---- one-time zero-fill of dup-layout bytes the per-iteration commit never
    // writes: positions NVALID..SIN_N-1 (P2 over-reach + ky=3 row; MFMA 0*NaN=NaN).
    {
        bf4 z;
        z[0] = (__bf16)0.0f; z[1] = (__bf16)0.0f; z[2] = (__bf16)0.0f; z[3] = (__bf16)0.0f;
        for (int pos = NVALID + tid; pos < SIN_N; pos += NTHREADS) {
            *(bf4*)&s_in[pos * 8] = z;         // entry pos, low 8B
            *(bf4*)&s_in[pos * 8 - 4] = z;     // entry pos-1, high 8B
        }
    }

    // loop-invariant staging coordinates (2 halo entries per thread)
    const int rA = tid / S, cA = tid - rA * S;
    const int tidB = tid + NTHREADS;
    const int rB = tidB / S, cB = tidB - rB * S;
    const bool haveB = tidB < NVALID;
    const int gxA = tx0 - 2 + cA;  const bool vxA = (unsigned)gxA < (unsigned)Ww;
    const int gxB = tx0 - 2 + cB;  const bool vxB = (unsigned)gxB < (unsigned)Ww;
    const float* wp0 = wind + (bb * 2 + 0) * HW_;
    const float* wp1 = wind + (bb * 2 + 1) * HW_;
    const float* tp  = topo + bb * HW_;
    const float* img = pm25 + bb * HW_;

    float sa0, sa1, sa2, sb0, sb1, sb2;
    auto stage = [&](int ty) {
        int gyA = ty - 2 + rA;
        bool vA = vxA && (unsigned)gyA < (unsigned)Hh;
        sa0 = 0.0f; sa1 = 0.0f; sa2 = 0.0f;
        if (vA) { int g = gyA * Ww + gxA; sa0 = wp0[g]; sa1 = wp1[g]; sa2 = tp[g]; }
        sb0 = 0.0f; sb1 = 0.0f; sb2 = 0.0f;
        if (haveB) {
            int gyB = ty - 2 + rB;
            bool vB = vxB && (unsigned)gyB < (unsigned)Hh;
            if (vB) { int g = gyB * Ww + gxB; sb0 = wp0[g]; sb1 = wp1[g]; sb2 = tp[g]; }
        }
    };

    stage(ty0);                        // prologue prefetch

    for (int it = 0; it < TPB; ++it) {
        // ---- A: commit staged halo regs to LDS (dup-entry layout) ----
        {
            bf4 v;
            v[0] = (__bf16)sa0; v[1] = (__bf16)sa1; v[2] = (__bf16)sa2; v[3] = (__bf16)1.0f;
            *(bf4*)&s_in[tid * 8] = v;
            if (tid > 0) *(bf4*)&s_in[tid * 8 - 4] = v;
            if (haveB) {
                bf4 w;
                w[0] = (__bf16)sb0; w[1] = (__bf16)sb1; w[2] = (__bf16)sb2; w[3] = (__bf16)1.0f;
                *(bf4*)&s_in[tidB * 8] = w;
                *(bf4*)&s_in[tidB * 8 - 4] = w;
            }
        }
        __syncthreads();               // B1: s_in ready; fences prev P3 feat reads too

        // ---- prefetch next tile's halo (covered by P2+P3+P4) ----
        if (it + 1 < TPB) stage(ty0 + TH);

        const bool edge = (ty0 == 0) || (ty0 == Hh - TH) || (tx0 == 0) || (tx0 == Ww - TW);

        // ---- P2: conv1 via MFMA 16x16x32, 6 uniform tiles/wave, 2-deep ILP ----
        {
            const int n    = lane & 15;
            const int kq   = lane >> 4;
            const int qoff = (kq >> 1) * S + (kq & 1) * 2;
            #pragma unroll 2
            for (int ii = 0; ii < 6; ++ii) {
                const int p = (wv + 8 * ii) * 16 + n;       // p <= 767
                f32x4 acc;
                acc[0] = 0.0f; acc[1] = 0.0f; acc[2] = 0.0f; acc[3] = 0.0f;
                bfrag bx0 = *(const bfrag*)&s_in[(p + qoff) * 8];
                bfrag bx1 = *(const bfrag*)&s_in[(p + qoff + 2 * S) * 8];
                acc = __builtin_amdgcn_mfma_f32_16x16x32_bf16(w1f0, bx0, acc, 0, 0, 0);
                acc = __builtin_amdgcn_mfma_f32_16x16x32_bf16(w1f1, bx1, acc, 0, 0, 0);
                f32x2 g0 = gelu_fast2(mk2(acc[0], acc[1]));
                f32x2 g1 = gelu_fast2(mk2(acc[2], acc[3]));
                if (edge) {
                    int fy = p / S;
                    int fx = p - fy * S;
                    int gy = ty0 + fy - 1, gx = tx0 + fx - 1;
                    float msk = ((unsigned)gy < (unsigned)Hh && (unsigned)gx < (unsigned)Ww)
                                ? 1.0f : 0.0f;
                    g0 *= msk; g1 *= msk;
                }
                bf4 w4;
                w4[0] = (__bf16)g0.x; w4[1] = (__bf16)g0.y;
                w4[2] = (__bf16)g1.x; w4[3] = (__bf16)g1.y;
                *(bf4*)&s_feat[((kq >> 1) * NFP + p) * 8 + (kq & 1) * 4] = w4;
            }
        }
        __syncthreads();               // B2: s_feat ready; fences s_in reads for next A

        // ---- P3: conv2 via MFMA 32x32x16, 12 shared fragments ----
        ffrag a0, a1;
        #pragma unroll
        for (int r = 0; r < 16; ++r) { a0[r] = 0.0f; a1[r] = 0.0f; }
        {
            const int vb = (lh * NFP + (2 * wv) * S + l31) * 8;
            #pragma unroll
            for (int kx = 0; kx < 3; ++kx) {
                bfrag f0 = *(const bfrag*)&s_feat[vb + (0 * S + kx) * 8];
                bfrag f1 = *(const bfrag*)&s_feat[vb + (1 * S + kx) * 8];
                bfrag f2 = *(const bfrag*)&s_feat[vb + (2 * S + kx) * 8];
                bfrag f3 = *(const bfrag*)&s_feat[vb + (3 * S + kx) * 8];
                bfrag w0  = WF[(0 * 3 + kx) * 64 + lane];
                bfrag w1_ = WF[(1 * 3 + kx) * 64 + lane];
                bfrag w2_ = WF[(2 * 3 + kx) * 64 + lane];
                a0 = __builtin_amdgcn_mfma_f32_32x32x16_bf16(w0,  f0, a0, 0, 0, 0);
                a1 = __builtin_amdgcn_mfma_f32_32x32x16_bf16(w0,  f1, a1, 0, 0, 0);
                a0 = __builtin_amdgcn_mfma_f32_32x32x16_bf16(w1_, f1, a0, 0, 0, 0);
                a1 = __builtin_amdgcn_mfma_f32_32x32x16_bf16(w1_, f2, a1, 0, 0, 0);
                a0 = __builtin_amdgcn_mfma_f32_32x32x16_bf16(w2_, f2, a0, 0, 0, 0);
                a1 = __builtin_amdgcn_mfma_f32_32x32x16_bf16(w2_, f3, a1, 0, 0, 0);
            }
        }

        // ---- P4: lazy per-active-tap exchange, one bilinear sample per lane ----
        {
            const int py_i = ty0 + 2 * wv + lh;
            const int px_i = tx0 + l31;
            const float fy = (float)py_i, fx = (float)px_i;
            float o = 0.0f;
            #pragma unroll
            for (int t = 0; t < 9; ++t) {
                float wk = wt[t];                        // uniform -> scalar branch
                if (wk != 0.0f) {
                    const int o_h = (t >> 1) & 1;                  // owner lane-half
                    const int rg  = ((2 * t) & 3) + 4 * (t >> 2);  // dy reg; dx = rg+1
                    float dy, dx;
                    if (o_h == 0) {
                        float sy = __shfl_xor(a1[rg], 32);
                        float sx = __shfl_xor(a1[rg + 1], 32);
                        dy = lh ? sy : a0[rg];
                        dx = lh ? sx : a0[rg + 1];
                    } else {
                        float sy = __shfl_xor(a0[rg], 32);
                        float sx = __shfl_xor(a0[rg + 1], 32);
                        dy = lh ? a1[rg] : sy;
                        dx = lh ? a1[rg + 1] : sx;
                    }
                    dy += b2[2 * t];
                    dx += b2[2 * t + 1];
                    float py = fy + (float)(t / 3 - 1) + dy;
                    float px = fx + (float)(t % 3 - 1) + dx;
                    o += wk * bilin(img, py, px);
                }
            }
            out[bb * HW_ + py_i * Ww + px_i] = o;
        }

        ty0 += TH;
    }
}

extern "C" void kernel_launch(void* const* d_in, const int* in_sizes, int n_in,
                              void* d_out, int out_size, void* d_ws, size_t ws_size,
                              hipStream_t stream) {
    const float* pm25 = (const float*)d_in[0];
    const float* wind = (const float*)d_in[1];
    const float* topo = (const float*)d_in[2];
    const float* w1   = (const float*)d_in[3];
    const float* b1   = (const float*)d_in[4];
    const float* w2   = (const float*)d_in[5];
    const float* b2   = (const float*)d_in[6];
    const float* wt   = (const float*)d_in[7];
    float* o          = (float*)d_out;
    int*   wsB        = (int*)d_ws;   // 576+128 int4 = 11264 B

    pack_w<<<dim3(1), dim3(64), 0, stream>>>(w2, w1, b1, wsB);

    dim3 grid(Ww / TW, Hh / (TH * TPB), Bn);   // 16 x 4 x 16 = 1024 blocks
    residual_advection_fused<<<grid, dim3(NTHREADS), 0, stream>>>(
        pm25, wind, topo, b2, wt, wsB, o);
}

// Round 8
// 190.878 us; speedup vs baseline: 1.7692x; 1.5859x over previous
//
#include <hip/hip_runtime.h>
#include <math.h>

#define Bn 16
#define Hh 512
#define Ww 512
#define HW_ (Hh * Ww)
#define TW 32                // tile width
#define TH 8                 // tile height (1 output row per wave)
#define NTHREADS 512
#define TPB 16               // tiles walked per block (vertical)
#define S 37                 // unified grid stride (input halo & feat grids)
#define NROWS 12             // input halo rows (TH+4)
#define NVALID (NROWS * S)   // 444 staged halo positions
#define SIN_N 512            // s_in entries allocated (max read idx 496)
#define NFP 384              // feat positions per 8-ch half (24 tiles * 16)
#define NT 24                // conv1 position tiles of 16
#define W2OFF (SIN_N * 16 + 2 * NFP * 16)        // 8192 + 12288 = 20480
#define SMEM_BYTES (W2OFF + 9216)                // + w2 frag table = 29696

typedef __bf16 bfrag __attribute__((ext_vector_type(8)));
typedef __bf16 bf4   __attribute__((ext_vector_type(4)));
typedef float  ffrag __attribute__((ext_vector_type(16)));
typedef float  f32x4 __attribute__((ext_vector_type(4)));
typedef float  f32x2 __attribute__((ext_vector_type(2)));

__device__ __forceinline__ short f2bf(float f) {           // RNE fp32 -> bf16 bits
    unsigned u = __float_as_uint(f);
    unsigned r = u + 0x7FFFu + ((u >> 16) & 1u);
    return (short)(r >> 16);
}

__device__ __forceinline__ f32x2 mk2(float a, float b) { f32x2 t; t.x = a; t.y = b; return t; }

// gelu exact-form via trans-free erf polynomial (same numerics as R3/R4)
__device__ __forceinline__ f32x2 gelu_fast2(f32x2 x) {
    const float C0 = 1.1259890f, C1 = -0.3565430f, C2 = 0.0848830f,
                C3 = -0.0110610f, C4 = 0.0005820f;
    f32x2 y = x * 0.70710678f;
    f32x2 t;
    t.x = fminf(fmaxf(y.x, -2.5f), 2.5f);
    t.y = fminf(fmaxf(y.y, -2.5f), 2.5f);
    f32x2 u = t * t;
    f32x2 p = u * C4 + C3;
    p = p * u + C2;
    p = p * u + C1;
    p = p * u + C0;
    f32x2 e = t * p;                 // ~erf(y)
    f32x2 h = x * 0.5f;
    return h * e + h;                // 0.5x(1+erf)
}

__device__ __forceinline__ float bilin(const float* __restrict__ img, float py, float px) {
    float y0f = floorf(py), x0f = floorf(px);
    float wy = py - y0f, wx = px - x0f;
    int y0 = (int)y0f, x0 = (int)x0f;
    int yc0 = min(max(y0, 0), Hh - 1), yc1 = min(max(y0 + 1, 0), Hh - 1);
    int xc0 = min(max(x0, 0), Ww - 1), xc1 = min(max(x0 + 1, 0), Ww - 1);
    bool vy0 = (unsigned)y0 < (unsigned)Hh, vy1 = (unsigned)(y0 + 1) < (unsigned)Hh;
    bool vx0 = (unsigned)x0 < (unsigned)Ww, vx1 = (unsigned)(x0 + 1) < (unsigned)Ww;
    const float* r0 = img + yc0 * Ww;
    const float* r1 = img + yc1 * Ww;
    float v00 = (vy0 && vx0) ? r0[xc0] : 0.0f;
    float v01 = (vy0 && vx1) ? r0[xc1] : 0.0f;
    float v10 = (vy1 && vx0) ? r1[xc0] : 0.0f;
    float v11 = (vy1 && vx1) ? r1[xc1] : 0.0f;
    return (1.0f - wy) * ((1.0f - wx) * v00 + wx * v01) +
           wy          * ((1.0f - wx) * v10 + wx * v11);
}

// ---- pre-pass: pack w2 A-frags (9 taps, 32x32x16) + w1 A-frags (2, 16x16x32) ----
__global__ void pack_w(const float* __restrict__ w2, const float* __restrict__ w1,
                       const float* __restrict__ b1, int* __restrict__ ws) {
    const int lane = threadIdx.x;            // 64 threads
    const int l31  = lane & 31;
    const int lh   = lane >> 5;
    for (int tap = 0; tap < 9; ++tap) {
        int pk[4];
        #pragma unroll
        for (int jj = 0; jj < 4; ++jj) {
            float v0 = (l31 < 18) ? w2[(l31 * 16 + lh * 8 + 2 * jj    ) * 9 + tap] : 0.0f;
            float v1 = (l31 < 18) ? w2[(l31 * 16 + lh * 8 + 2 * jj + 1) * 9 + tap] : 0.0f;
            pk[jj] = ((int)(unsigned short)f2bf(v0)) | ((int)f2bf(v1) << 16);
        }
        ((int4*)ws)[tap * 64 + lane] = make_int4(pk[0], pk[1], pk[2], pk[3]);
    }
    const int m  = lane & 15;
    const int kq = lane >> 4;
    for (int t = 0; t < 2; ++t) {
        int pk[4];
        #pragma unroll
        for (int jj = 0; jj < 4; ++jj) {
            float vv[2];
            #pragma unroll
            for (int h = 0; h < 2; ++h) {
                int k   = kq * 8 + 2 * jj + h;
                int kyl = k >> 4, kx = (k >> 2) & 3, c = k & 3;
                int ky  = 2 * t + kyl;
                float x = 0.0f;
                if (kx < 3 && c < 3 && ky < 3) x = w1[m * 27 + c * 9 + ky * 3 + kx];
                if (t == 0 && k == 3) x = b1[m];     // bias slot (reads const-1.0 channel)
                vv[h] = x;
            }
            pk[jj] = ((int)(unsigned short)f2bf(vv[0])) | ((int)f2bf(vv[1]) << 16);
        }
        ((int4*)ws)[576 + t * 64 + lane] = make_int4(pk[0], pk[1], pk[2], pk[3]);
    }
}

__global__ __launch_bounds__(NTHREADS, 8) void residual_advection_fused(
    const float* __restrict__ pm25,   // (16,1,512,512)
    const float* __restrict__ wind,   // (16,2,512,512)
    const float* __restrict__ topo,   // (16,1,512,512)
    const float* __restrict__ b2,     // (18)
    const float* __restrict__ wt,     // (9)
    const int*   __restrict__ wsB,    // packed w2 + w1 A-fragments
    float* __restrict__ out)          // (16,1,512,512)
{
    __shared__ __align__(16) char smem[SMEM_BYTES];
    __bf16* s_in   = (__bf16*)smem;                  // dup entries, 16B each
    __bf16* s_feat = (__bf16*)(smem + SIN_N * 16);   // [2][NFP][8]

    const int tid = threadIdx.x;
    const int bb  = blockIdx.z;
    const int tx0 = blockIdx.x * TW;
    int ty0 = blockIdx.y * (TPB * TH);

    const int lane = tid & 63;
    const int wv   = tid >> 6;       // 0..7  (one output row per wave)
    const int l31  = lane & 31;
    const int lh   = lane >> 5;

    const bfrag* WF = (const bfrag*)wsB;
    bfrag w1f0 = WF[576 + lane];
    bfrag w1f1 = WF[640 + lane];

    // ---- one-time: copy w2 frag table to LDS (9216 B). Reading it from LDS
    // inside the loop (with intervening s_feat ds_writes) prevents LICM from
    // hoisting 36 VGPRs of loop-invariant fragments -- the R6/R7 spill cause.
    for (int idx = tid; idx < 576; idx += NTHREADS)
        ((int4*)(smem + W2OFF))[idx] = ((const int4*)wsB)[idx];

    // ---- one-time zero-fill of dup-layout bytes the per-iteration commit never
    // writes: positions NVALID..SIN_N-1 (P2 over-reach + ky=3 row; MFMA 0*NaN=NaN).
    {
        bf4 z;
        z[0] = (__bf16)0.0f; z[1] = (__bf16)0.0f; z[2] = (__bf16)0.0f; z[3] = (__bf16)0.0f;
        for (int pos = NVALID + tid; pos < SIN_N; pos += NTHREADS) {
            *(bf4*)&s_in[pos * 8] = z;         // entry pos, low 8B
            *(bf4*)&s_in[pos * 8 - 4] = z;     // entry pos-1, high 8B
        }
    }

    // loop-invariant staging coordinates (1 halo entry per thread, 444 active)
    const int rA = tid / S, cA = tid - rA * S;
    const bool haveA = tid < NVALID;
    const int gxA = tx0 - 2 + cA;
    const bool vxA = (unsigned)gxA < (unsigned)Ww;
    const float* wp0 = wind + (bb * 2 + 0) * HW_;
    const float* wp1 = wind + (bb * 2 + 1) * HW_;
    const float* tp  = topo + bb * HW_;
    const float* img = pm25 + bb * HW_;

    float sa0, sa1, sa2;
    auto stage = [&](int ty) {
        sa0 = 0.0f; sa1 = 0.0f; sa2 = 0.0f;
        if (haveA) {
            int gyA = ty - 2 + rA;
            if (vxA && (unsigned)gyA < (unsigned)Hh) {
                int g = gyA * Ww + gxA;
                sa0 = wp0[g]; sa1 = wp1[g]; sa2 = tp[g];
            }
        }
    };

    stage(ty0);                        // prologue prefetch

    for (int it = 0; it < TPB; ++it) {
        // ---- A: commit staged halo regs to LDS (dup-entry layout) ----
        if (haveA) {
            bf4 v;
            v[0] = (__bf16)sa0; v[1] = (__bf16)sa1; v[2] = (__bf16)sa2; v[3] = (__bf16)1.0f;
            *(bf4*)&s_in[tid * 8] = v;
            if (tid > 0) *(bf4*)&s_in[tid * 8 - 4] = v;
        }
        __syncthreads();               // B1: s_in ready; fences prev P3 feat reads too

        // ---- prefetch next tile's halo (covered by P2+P3+P4) ----
        if (it + 1 < TPB) stage(ty0 + TH);

        const bool edge = (ty0 == 0) || (ty0 == Hh - TH) || (tx0 == 0) || (tx0 == Ww - TW);

        // ---- P2: conv1 via MFMA 16x16x32, 3 uniform tiles/wave ----
        {
            const int n    = lane & 15;
            const int kq   = lane >> 4;
            const int qoff = (kq >> 1) * S + (kq & 1) * 2;
            #pragma unroll 1
            for (int ii = 0; ii < 3; ++ii) {
                const int p = (wv + 8 * ii) * 16 + n;       // p <= 383
                f32x4 acc;
                acc[0] = 0.0f; acc[1] = 0.0f; acc[2] = 0.0f; acc[3] = 0.0f;
                bfrag bx0 = *(const bfrag*)&s_in[(p + qoff) * 8];
                bfrag bx1 = *(const bfrag*)&s_in[(p + qoff + 2 * S) * 8];
                acc = __builtin_amdgcn_mfma_f32_16x16x32_bf16(w1f0, bx0, acc, 0, 0, 0);
                acc = __builtin_amdgcn_mfma_f32_16x16x32_bf16(w1f1, bx1, acc, 0, 0, 0);
                f32x2 g0 = gelu_fast2(mk2(acc[0], acc[1]));
                f32x2 g1 = gelu_fast2(mk2(acc[2], acc[3]));
                if (edge) {
                    int fy = p / S;
                    int fx = p - fy * S;
                    int gy = ty0 + fy - 1, gx = tx0 + fx - 1;
                    float msk = ((unsigned)gy < (unsigned)Hh && (unsigned)gx < (unsigned)Ww)
                                ? 1.0f : 0.0f;
                    g0 *= msk; g1 *= msk;
                }
                bf4 w4;
                w4[0] = (__bf16)g0.x; w4[1] = (__bf16)g0.y;
                w4[2] = (__bf16)g1.x; w4[3] = (__bf16)g1.y;
                *(bf4*)&s_feat[((kq >> 1) * NFP + p) * 8 + (kq & 1) * 4] = w4;
            }
        }
        __syncthreads();               // B2: s_feat ready; fences s_in reads for next A

        // ---- P3: conv2 via MFMA 32x32x16, one chain (row ty0+wv, 32 px) ----
        ffrag a0;
        #pragma unroll
        for (int r = 0; r < 16; ++r) a0[r] = 0.0f;
        {
            const int vb = (lh * NFP + wv * S + l31) * 8;
            const bfrag* SW = (const bfrag*)(smem + W2OFF);
            #pragma unroll
            for (int ky = 0; ky < 3; ++ky)
                #pragma unroll
                for (int kx = 0; kx < 3; ++kx) {
                    bfrag f = *(const bfrag*)&s_feat[vb + (ky * S + kx) * 8];
                    bfrag w = SW[(ky * 3 + kx) * 64 + lane];
                    a0 = __builtin_amdgcn_mfma_f32_32x32x16_bf16(w, f, a0, 0, 0, 0);
                }
        }

        // ---- P4: owning lane-half samples its taps directly, then half-sum ----
        // C/D: col = pixel = l31, row = co = (reg&3)+8*(reg>>2)+4*lh.
        // Tap t rows (2t,2t+1) live in half (t>>1)&1 at regs rg,rg+1.
        {
            const int py_i = ty0 + wv;
            const int px_i = tx0 + l31;
            const float fy = (float)py_i, fx = (float)px_i;
            float o = 0.0f;
            #pragma unroll
            for (int t = 0; t < 9; ++t) {
                float wk = wt[t];                        // uniform -> scalar branch
                if (wk != 0.0f) {
                    const int o_h = (t >> 1) & 1;                  // owner lane-half
                    if (o_h == lh) {
                        const int rg = ((2 * t) & 3) + 4 * (t >> 2);
                        float dy = a0[rg]     + b2[2 * t];
                        float dx = a0[rg + 1] + b2[2 * t + 1];
                        float py = fy + (float)(t / 3 - 1) + dy;
                        float px = fx + (float)(t % 3 - 1) + dx;
                        o += wk * bilin(img, py, px);
                    }
                }
            }
            o += __shfl_xor(o, 32);            // combine tap-halves per pixel
            if (!lh) out[bb * HW_ + py_i * Ww + px_i] = o;
        }

        ty0 += TH;
    }
}

extern "C" void kernel_launch(void* const* d_in, const int* in_sizes, int n_in,
                              void* d_out, int out_size, void* d_ws, size_t ws_size,
                              hipStream_t stream) {
    const float* pm25 = (const float*)d_in[0];
    const float* wind = (const float*)d_in[1];
    const float* topo = (const float*)d_in[2];
    const float* w1   = (const float*)d_in[3];
    const float* b1   = (const float*)d_in[4];
    const float* w2   = (const float*)d_in[5];
    const float* b2   = (const float*)d_in[6];
    const float* wt   = (const float*)d_in[7];
    float* o          = (float*)d_out;
    int*   wsB        = (int*)d_ws;   // 576+128 int4 = 11264 B

    pack_w<<<dim3(1), dim3(64), 0, stream>>>(w2, w1, b1, wsB);

    dim3 grid(Ww / TW, Hh / (TH * TPB), Bn);   // 16 x 4 x 16 = 1024 blocks
    residual_advection_fused<<<grid, dim3(NTHREADS), 0, stream>>>(
        pm25, wind, topo, b2, wt, wsB, o);
}

// Round 9
// 178.163 us; speedup vs baseline: 1.8954x; 1.0714x over previous
//
#include <hip/hip_runtime.h>
#include <math.h>

#define Bn 16
#define Hh 512
#define Ww 512
#define HW_ (Hh * Ww)
#define TW 32                // tile width
#define TH 16                // tile height
#define NTHREADS 512
#define TPB 4                // tiles walked per block (vertical)
#define S 37                 // unified grid stride (input halo & feat grids)
#define NROWS 20             // input halo rows (TH+4)
#define NVALID (NROWS * S)   // 740 staged halo positions
#define SIN_N 912            // s_in entries allocated (max read idx 880)
#define NFP 800              // feat positions per 8-ch half (48 tiles * 16 = 768, pad)
#define W2OFF (SIN_N * 16 + 2 * NFP * 16)        // 14592 + 25600 = 40192
#define SMEM_BYTES (W2OFF + 9216)                // + w2 frag table = 49408 -> 3 blocks/CU

// raw barrier: LDS-visibility only -- does NOT drain vmcnt, so prefetch loads,
// gather loads and out-stores stay in flight across it (the R4..R8 plateau was
// __syncthreads()'s vmcnt(0) drain serializing every global round-trip).
#define BAR() do { \
    asm volatile("s_waitcnt lgkmcnt(0)" ::: "memory"); \
    __builtin_amdgcn_s_barrier(); \
    __builtin_amdgcn_sched_barrier(0); \
} while (0)

typedef __bf16 bfrag __attribute__((ext_vector_type(8)));
typedef __bf16 bf4   __attribute__((ext_vector_type(4)));
typedef float  ffrag __attribute__((ext_vector_type(16)));
typedef float  f32x4 __attribute__((ext_vector_type(4)));
typedef float  f32x2 __attribute__((ext_vector_type(2)));

__device__ __forceinline__ short f2bf(float f) {           // RNE fp32 -> bf16 bits
    unsigned u = __float_as_uint(f);
    unsigned r = u + 0x7FFFu + ((u >> 16) & 1u);
    return (short)(r >> 16);
}

__device__ __forceinline__ f32x2 mk2(float a, float b) { f32x2 t; t.x = a; t.y = b; return t; }

// gelu exact-form via trans-free erf polynomial (same numerics as R3/R4)
__device__ __forceinline__ f32x2 gelu_fast2(f32x2 x) {
    const float C0 = 1.1259890f, C1 = -0.3565430f, C2 = 0.0848830f,
                C3 = -0.0110610f, C4 = 0.0005820f;
    f32x2 y = x * 0.70710678f;
    f32x2 t;
    t.x = fminf(fmaxf(y.x, -2.5f), 2.5f);
    t.y = fminf(fmaxf(y.y, -2.5f), 2.5f);
    f32x2 u = t * t;
    f32x2 p = u * C4 + C3;
    p = p * u + C2;
    p = p * u + C1;
    p = p * u + C0;
    f32x2 e = t * p;                 // ~erf(y)
    f32x2 h = x * 0.5f;
    return h * e + h;                // 0.5x(1+erf)
}

__device__ __forceinline__ float bilin(const float* __restrict__ img, float py, float px) {
    float y0f = floorf(py), x0f = floorf(px);
    float wy = py - y0f, wx = px - x0f;
    int y0 = (int)y0f, x0 = (int)x0f;
    int yc0 = min(max(y0, 0), Hh - 1), yc1 = min(max(y0 + 1, 0), Hh - 1);
    int xc0 = min(max(x0, 0), Ww - 1), xc1 = min(max(x0 + 1, 0), Ww - 1);
    bool vy0 = (unsigned)y0 < (unsigned)Hh, vy1 = (unsigned)(y0 + 1) < (unsigned)Hh;
    bool vx0 = (unsigned)x0 < (unsigned)Ww, vx1 = (unsigned)(x0 + 1) < (unsigned)Ww;
    const float* r0 = img + yc0 * Ww;
    const float* r1 = img + yc1 * Ww;
    float v00 = (vy0 && vx0) ? r0[xc0] : 0.0f;
    float v01 = (vy0 && vx1) ? r0[xc1] : 0.0f;
    float v10 = (vy1 && vx0) ? r1[xc0] : 0.0f;
    float v11 = (vy1 && vx1) ? r1[xc1] : 0.0f;
    return (1.0f - wy) * ((1.0f - wx) * v00 + wx * v01) +
           wy          * ((1.0f - wx) * v10 + wx * v11);
}

// ---- pre-pass: pack w2 A-frags (9 taps, 32x32x16) + w1 A-frags (2, 16x16x32) ----
__global__ void pack_w(const float* __restrict__ w2, const float* __restrict__ w1,
                       const float* __restrict__ b1, int* __restrict__ ws) {
    const int lane = threadIdx.x;            // 64 threads
    const int l31  = lane & 31;
    const int lh   = lane >> 5;
    for (int tap = 0; tap < 9; ++tap) {
        int pk[4];
        #pragma unroll
        for (int jj = 0; jj < 4; ++jj) {
            float v0 = (l31 < 18) ? w2[(l31 * 16 + lh * 8 + 2 * jj    ) * 9 + tap] : 0.0f;
            float v1 = (l31 < 18) ? w2[(l31 * 16 + lh * 8 + 2 * jj + 1) * 9 + tap] : 0.0f;
            pk[jj] = ((int)(unsigned short)f2bf(v0)) | ((int)f2bf(v1) << 16);
        }
        ((int4*)ws)[tap * 64 + lane] = make_int4(pk[0], pk[1], pk[2], pk[3]);
    }
    const int m  = lane & 15;
    const int kq = lane >> 4;
    for (int t = 0; t < 2; ++t) {
        int pk[4];
        #pragma unroll
        for (int jj = 0; jj < 4; ++jj) {
            float vv[2];
            #pragma unroll
            for (int h = 0; h < 2; ++h) {
                int k   = kq * 8 + 2 * jj + h;
                int kyl = k >> 4, kx = (k >> 2) & 3, c = k & 3;
                int ky  = 2 * t + kyl;
                float x = 0.0f;
                if (kx < 3 && c < 3 && ky < 3) x = w1[m * 27 + c * 9 + ky * 3 + kx];
                if (t == 0 && k == 3) x = b1[m];     // bias slot (reads const-1.0 channel)
                vv[h] = x;
            }
            pk[jj] = ((int)(unsigned short)f2bf(vv[0])) | ((int)f2bf(vv[1]) << 16);
        }
        ((int4*)ws)[576 + t * 64 + lane] = make_int4(pk[0], pk[1], pk[2], pk[3]);
    }
}

__global__ __launch_bounds__(NTHREADS, 6) void residual_advection_fused(
    const float* __restrict__ pm25,   // (16,1,512,512)
    const float* __restrict__ wind,   // (16,2,512,512)
    const float* __restrict__ topo,   // (16,1,512,512)
    const float* __restrict__ b2,     // (18)
    const float* __restrict__ wt,     // (9)
    const int*   __restrict__ wsB,    // packed w2 + w1 A-fragments
    float* __restrict__ out)          // (16,1,512,512)
{
    __shared__ __align__(16) char smem[SMEM_BYTES];
    __bf16* s_in   = (__bf16*)smem;                  // dup entries, 16B each
    __bf16* s_feat = (__bf16*)(smem + SIN_N * 16);   // [2][NFP][8]

    const int tid = threadIdx.x;
    const int bb  = blockIdx.z;
    const int tx0 = blockIdx.x * TW;
    int ty0 = blockIdx.y * (TPB * TH);

    const int lane = tid & 63;
    const int wv   = tid >> 6;       // 0..7
    const int l31  = lane & 31;
    const int lh   = lane >> 5;

    const bfrag* WF = (const bfrag*)wsB;
    bfrag w1f0 = WF[576 + lane];
    bfrag w1f1 = WF[640 + lane];

    // one-time: copy w2 frag table to LDS (anti-LICM: keeps 36 VGPRs free, R8 fix)
    for (int idx = tid; idx < 576; idx += NTHREADS)
        ((int4*)(smem + W2OFF))[idx] = ((const int4*)wsB)[idx];

    // one-time zero-fill of dup-layout bytes never written per-iteration
    // (P2 over-reach + ky=3 zero-weight row; MFMA 0*NaN = NaN -- R6 fix)
    {
        bf4 z;
        z[0] = (__bf16)0.0f; z[1] = (__bf16)0.0f; z[2] = (__bf16)0.0f; z[3] = (__bf16)0.0f;
        for (int pos = NVALID + tid; pos < SIN_N; pos += NTHREADS) {
            *(bf4*)&s_in[pos * 8] = z;         // entry pos, low 8B
            *(bf4*)&s_in[pos * 8 - 4] = z;     // entry pos-1, high 8B
        }
    }

    // loop-invariant staging coordinates (2 halo entries per thread)
    const int rA = tid / S, cA = tid - rA * S;
    const int tidB = tid + NTHREADS;
    const int rB = tidB / S, cB = tidB - rB * S;
    const bool haveB = tidB < NVALID;
    const int gxA = tx0 - 2 + cA;  const bool vxA = (unsigned)gxA < (unsigned)Ww;
    const int gxB = tx0 - 2 + cB;  const bool vxB = (unsigned)gxB < (unsigned)Ww;
    const float* wp0 = wind + (bb * 2 + 0) * HW_;
    const float* wp1 = wind + (bb * 2 + 1) * HW_;
    const float* tp  = topo + bb * HW_;
    const float* img = pm25 + bb * HW_;

    float sa0, sa1, sa2, sb0, sb1, sb2;
    auto stage = [&](int ty) {
        int gyA = ty - 2 + rA;
        bool vA = vxA && (unsigned)gyA < (unsigned)Hh;
        sa0 = 0.0f; sa1 = 0.0f; sa2 = 0.0f;
        if (vA) { int g = gyA * Ww + gxA; sa0 = wp0[g]; sa1 = wp1[g]; sa2 = tp[g]; }
        sb0 = 0.0f; sb1 = 0.0f; sb2 = 0.0f;
        if (haveB) {
            int gyB = ty - 2 + rB;
            bool vB = vxB && (unsigned)gyB < (unsigned)Hh;
            if (vB) { int g = gyB * Ww + gxB; sb0 = wp0[g]; sb1 = wp1[g]; sb2 = tp[g]; }
        }
    };

    stage(ty0);                        // prologue prefetch

    for (int it = 0; it < TPB; ++it) {
        // ---- A: commit staged halo regs to LDS (dup-entry layout) ----
        {
            bf4 v;
            v[0] = (__bf16)sa0; v[1] = (__bf16)sa1; v[2] = (__bf16)sa2; v[3] = (__bf16)1.0f;
            *(bf4*)&s_in[tid * 8] = v;
            if (tid > 0) *(bf4*)&s_in[tid * 8 - 4] = v;
            if (haveB) {
                bf4 w;
                w[0] = (__bf16)sb0; w[1] = (__bf16)sb1; w[2] = (__bf16)sb2; w[3] = (__bf16)1.0f;
                *(bf4*)&s_in[tidB * 8] = w;
                *(bf4*)&s_in[tidB * 8 - 4] = w;
            }
        }
        BAR();                         // B1: s_in ready (LDS-only drain)

        // ---- prefetch next tile's halo: stays IN FLIGHT across B2 (no vmcnt drain)
        if (it + 1 < TPB) stage(ty0 + TH);

        const bool edge = (ty0 == 0) || (ty0 == Hh - TH) || (tx0 == 0) || (tx0 == Ww - TW);

        // ---- P2: conv1 via MFMA 16x16x32, 6 uniform tiles/wave, 2-deep ILP ----
        {
            const int n    = lane & 15;
            const int kq   = lane >> 4;
            const int qoff = (kq >> 1) * S + (kq & 1) * 2;
            #pragma unroll 2
            for (int ii = 0; ii < 6; ++ii) {
                const int p = (wv + 8 * ii) * 16 + n;       // p <= 767
                f32x4 acc;
                acc[0] = 0.0f; acc[1] = 0.0f; acc[2] = 0.0f; acc[3] = 0.0f;
                bfrag bx0 = *(const bfrag*)&s_in[(p + qoff) * 8];
                bfrag bx1 = *(const bfrag*)&s_in[(p + qoff + 2 * S) * 8];
                acc = __builtin_amdgcn_mfma_f32_16x16x32_bf16(w1f0, bx0, acc, 0, 0, 0);
                acc = __builtin_amdgcn_mfma_f32_16x16x32_bf16(w1f1, bx1, acc, 0, 0, 0);
                f32x2 g0 = gelu_fast2(mk2(acc[0], acc[1]));
                f32x2 g1 = gelu_fast2(mk2(acc[2], acc[3]));
                if (edge) {
                    int fy = p / S;
                    int fx = p - fy * S;
                    int gy = ty0 + fy - 1, gx = tx0 + fx - 1;
                    float msk = ((unsigned)gy < (unsigned)Hh && (unsigned)gx < (unsigned)Ww)
                                ? 1.0f : 0.0f;
                    g0 *= msk; g1 *= msk;
                }
                bf4 w4;
                w4[0] = (__bf16)g0.x; w4[1] = (__bf16)g0.y;
                w4[2] = (__bf16)g1.x; w4[3] = (__bf16)g1.y;
                *(bf4*)&s_feat[((kq >> 1) * NFP + p) * 8 + (kq & 1) * 4] = w4;
            }
        }
        BAR();                         // B2: s_feat ready (LDS-only drain)

        // ---- P3: conv2 via MFMA 32x32x16, 12 shared feat frags, w2 from LDS ----
        ffrag a0, a1;
        #pragma unroll
        for (int r = 0; r < 16; ++r) { a0[r] = 0.0f; a1[r] = 0.0f; }
        {
            const int vb = (lh * NFP + (2 * wv) * S + l31) * 8;
            const bfrag* SW = (const bfrag*)(smem + W2OFF);
            #pragma unroll
            for (int kx = 0; kx < 3; ++kx) {
                bfrag f0 = *(const bfrag*)&s_feat[vb + (0 * S + kx) * 8];
                bfrag f1 = *(const bfrag*)&s_feat[vb + (1 * S + kx) * 8];
                bfrag f2 = *(const bfrag*)&s_feat[vb + (2 * S + kx) * 8];
                bfrag f3 = *(const bfrag*)&s_feat[vb + (3 * S + kx) * 8];
                bfrag w0  = SW[(0 * 3 + kx) * 64 + lane];
                bfrag w1_ = SW[(1 * 3 + kx) * 64 + lane];
                bfrag w2_ = SW[(2 * 3 + kx) * 64 + lane];
                a0 = __builtin_amdgcn_mfma_f32_32x32x16_bf16(w0,  f0, a0, 0, 0, 0);
                a1 = __builtin_amdgcn_mfma_f32_32x32x16_bf16(w0,  f1, a1, 0, 0, 0);
                a0 = __builtin_amdgcn_mfma_f32_32x32x16_bf16(w1_, f1, a0, 0, 0, 0);
                a1 = __builtin_amdgcn_mfma_f32_32x32x16_bf16(w1_, f2, a1, 0, 0, 0);
                a0 = __builtin_amdgcn_mfma_f32_32x32x16_bf16(w2_, f2, a0, 0, 0, 0);
                a1 = __builtin_amdgcn_mfma_f32_32x32x16_bf16(w2_, f3, a1, 0, 0, 0);
            }
        }

        // ---- P4: lazy per-active-tap exchange, one bilinear sample per lane ----
        // gather loads + out store are never vmcnt-drained by the loop barriers
        {
            const int py_i = ty0 + 2 * wv + lh;
            const int px_i = tx0 + l31;
            const float fy = (float)py_i, fx = (float)px_i;
            float o = 0.0f;
            #pragma unroll
            for (int t = 0; t < 9; ++t) {
                float wk = wt[t];                        // uniform -> scalar branch
                if (wk != 0.0f) {
                    const int o_h = (t >> 1) & 1;                  // owner lane-half
                    const int rg  = ((2 * t) & 3) + 4 * (t >> 2);  // dy reg; dx = rg+1
                    float dy, dx;
                    if (o_h == 0) {
                        float sy = __shfl_xor(a1[rg], 32);
                        float sx = __shfl_xor(a1[rg + 1], 32);
                        dy = lh ? sy : a0[rg];
                        dx = lh ? sx : a0[rg + 1];
                    } else {
                        float sy = __shfl_xor(a0[rg], 32);
                        float sx = __shfl_xor(a0[rg + 1], 32);
                        dy = lh ? a1[rg] : sy;
                        dx = lh ? a1[rg + 1] : sx;
                    }
                    dy += b2[2 * t];
                    dx += b2[2 * t + 1];
                    float py = fy + (float)(t / 3 - 1) + dy;
                    float px = fx + (float)(t % 3 - 1) + dx;
                    o += wk * bilin(img, py, px);
                }
            }
            out[bb * HW_ + py_i * Ww + px_i] = o;
        }

        ty0 += TH;
    }
}

extern "C" void kernel_launch(void* const* d_in, const int* in_sizes, int n_in,
                              void* d_out, int out_size, void* d_ws, size_t ws_size,
                              hipStream_t stream) {
    const float* pm25 = (const float*)d_in[0];
    const float* wind = (const float*)d_in[1];
    const float* topo = (const float*)d_in[2];
    const float* w1   = (const float*)d_in[3];
    const float* b1   = (const float*)d_in[4];
    const float* w2   = (const float*)d_in[5];
    const float* b2   = (const float*)d_in[6];
    const float* wt   = (const float*)d_in[7];
    float* o          = (float*)d_out;
    int*   wsB        = (int*)d_ws;   // 576+128 int4 = 11264 B

    pack_w<<<dim3(1), dim3(64), 0, stream>>>(w2, w1, b1, wsB);

    dim3 grid(Ww / TW, Hh / (TH * TPB), Bn);   // 16 x 8 x 16 = 2048 blocks
    residual_advection_fused<<<grid, dim3(NTHREADS), 0, stream>>>(
        pm25, wind, topo, b2, wt, wsB, o);
}